// Round 1
// baseline (880.416 us; speedup 1.0000x reference)
//
#include <hip/hip_runtime.h>

// Problem constants (fixed-shape problem: N=4096, D=256, K=8 coeffs)
#define NDIM 4096
#define DDIM 256
#define KORD 8

// GEMM tiling
#define BM 128
#define BN 64
#define BK 16
#define SPLITK 4
#define KSLICE (NDIM / SPLITK)   // 1024
#define TM 8
#define TN 4
// 256 threads: 16 col-groups (TN=4 each) x 16 row-groups (TM=8 each)

#define ELEMS (NDIM * DDIM)       // 1048576
#define VEC4  (ELEMS / 4)         // 262144

// ---------------- out = c0 * x ----------------
__global__ __launch_bounds__(256)
void poly_init(const float* __restrict__ x, float* __restrict__ out,
               const float* __restrict__ coeffs)
{
    const float c0 = coeffs[0];
    const int idx = blockIdx.x * 256 + threadIdx.x;   // float4 index
    float4 v = ((const float4*)x)[idx];
    float4 o;
    o.x = c0 * v.x; o.y = c0 * v.y; o.z = c0 * v.z; o.w = c0 * v.w;
    ((float4*)out)[idx] = o;
}

// ---------------- partial GEMM: P[sk] = A[:, kslice] @ B[kslice, :] ----------------
// A: [NDIM, NDIM] row-major (L), B: [NDIM, DDIM] row-major (y), P: [SPLITK][NDIM*DDIM]
__global__ __launch_bounds__(256, 2)
void poly_gemm_part(const float* __restrict__ A, const float* __restrict__ B,
                    float* __restrict__ P)
{
    __shared__ float As[BK][BM + 4];   // transposed: As[k][m], pad 4 keeps 16B align
    __shared__ float Bs[BK][BN + 4];

    const int nt = blockIdx.x;         // 0..3   (column tile)
    const int mt = blockIdx.y;         // 0..31  (row tile)
    const int sk = blockIdx.z;         // 0..3   (K slice)

    const int tid = threadIdx.x;
    const int tx = tid & 15;           // col group -> cols tx*4 .. +3
    const int ty = tid >> 4;           // row group -> rows ty*8 .. +7

    const int m0 = mt * BM;
    const int n0 = nt * BN;
    const int kbase = sk * KSLICE;

    // A staging: 2 float4 per thread along K
    const int arow = tid >> 2;           // 0..63 (+64 for second load)
    const int akq  = (tid & 3) << 2;     // k offset 0,4,8,12
    // B staging: 1 float4 per thread along N
    const int brow = tid >> 4;           // 0..15
    const int bnq  = (tid & 15) << 2;    // n offset

    float acc[TM][TN];
#pragma unroll
    for (int i = 0; i < TM; ++i)
#pragma unroll
        for (int j = 0; j < TN; ++j) acc[i][j] = 0.0f;

    for (int kt = 0; kt < KSLICE; kt += BK) {
        const int k0 = kbase + kt;

        // ---- stage A tile (rows m0..m0+127, cols k0..k0+15), transposed into LDS
#pragma unroll
        for (int r = 0; r < 2; ++r) {
            const int row = arow + r * 64;
            const float4 av = *(const float4*)&A[(m0 + row) * NDIM + k0 + akq];
            As[akq + 0][row] = av.x;
            As[akq + 1][row] = av.y;
            As[akq + 2][row] = av.z;
            As[akq + 3][row] = av.w;
        }
        // ---- stage B tile (rows k0..k0+15, cols n0..n0+63)
        {
            const float4 bv = *(const float4*)&B[(k0 + brow) * DDIM + n0 + bnq];
            *(float4*)&Bs[brow][bnq] = bv;
        }
        __syncthreads();

#pragma unroll
        for (int kk = 0; kk < BK; ++kk) {
            const float4 a0 = *(const float4*)&As[kk][ty * TM];
            const float4 a1 = *(const float4*)&As[kk][ty * TM + 4];
            const float4 b0 = *(const float4*)&Bs[kk][tx * TN];
            const float a[TM] = {a0.x, a0.y, a0.z, a0.w, a1.x, a1.y, a1.z, a1.w};
            const float b[TN] = {b0.x, b0.y, b0.z, b0.w};
#pragma unroll
            for (int i = 0; i < TM; ++i)
#pragma unroll
                for (int j = 0; j < TN; ++j)
                    acc[i][j] = fmaf(a[i], b[j], acc[i][j]);
        }
        __syncthreads();
    }

    // ---- write partial tile
    float* Pp = P + (size_t)sk * ELEMS;
#pragma unroll
    for (int i = 0; i < TM; ++i) {
        float4 v;
        v.x = acc[i][0]; v.y = acc[i][1]; v.z = acc[i][2]; v.w = acc[i][3];
        *(float4*)&Pp[(m0 + ty * TM + i) * DDIM + n0 + tx * TN] = v;
    }
}

// ---------------- combine: y = sum_s P[s];  out += c[ci] * y ----------------
__global__ __launch_bounds__(256)
void poly_combine(const float* __restrict__ P, float* __restrict__ ynew,
                  float* __restrict__ out, const float* __restrict__ coeffs,
                  int ci)
{
    const float c = coeffs[ci];
    const int idx = blockIdx.x * 256 + threadIdx.x;   // float4 index
    const float4* p = (const float4*)P;
    float4 s = p[idx];
#pragma unroll
    for (int sl = 1; sl < SPLITK; ++sl) {
        const float4 t = p[idx + sl * VEC4];
        s.x += t.x; s.y += t.y; s.z += t.z; s.w += t.w;
    }
    ((float4*)ynew)[idx] = s;
    float4 o = ((float4*)out)[idx];
    o.x = fmaf(c, s.x, o.x);
    o.y = fmaf(c, s.y, o.y);
    o.z = fmaf(c, s.z, o.z);
    o.w = fmaf(c, s.w, o.w);
    ((float4*)out)[idx] = o;
}

extern "C" void kernel_launch(void* const* d_in, const int* in_sizes, int n_in,
                              void* d_out, int out_size, void* d_ws, size_t ws_size,
                              hipStream_t stream)
{
    const float* L      = (const float*)d_in[0];   // [4096,4096]
    const float* x      = (const float*)d_in[1];   // [4096,256]
    const float* coeffs = (const float*)d_in[2];   // [8]
    float* out = (float*)d_out;                    // [4096,256]
    float* ws  = (float*)d_ws;

    float* part = ws;                              // SPLITK * ELEMS floats (16 MB)
    float* ybuf = ws + (size_t)SPLITK * ELEMS;     // ELEMS floats (4 MB)

    // out = c0 * x
    poly_init<<<VEC4 / 256, 256, 0, stream>>>(x, out, coeffs);

    const float* cur = x;
    for (int i = 1; i < KORD; ++i) {
        poly_gemm_part<<<dim3(DDIM / BN, NDIM / BM, SPLITK), 256, 0, stream>>>(L, cur, part);
        poly_combine<<<VEC4 / 256, 256, 0, stream>>>(part, ybuf, out, coeffs, i);
        cur = ybuf;
    }
}

// Round 2
// 429.289 us; speedup vs baseline: 2.0509x; 2.0509x over previous
//
#include <hip/hip_runtime.h>
#include <hip/hip_bf16.h>

#define NDIM 4096
#define DDIM 256
#define KORD 8

#define BM 128
#define BN 64
#define BK 32
#define KHALF 2048
#define NSLICE 6               // 3 products x 2 K-halves
#define ELEMS (NDIM * DDIM)    // 1048576

typedef __attribute__((ext_vector_type(8))) short bf16x8;
typedef __attribute__((ext_vector_type(4))) float f32x4;

__device__ __forceinline__ ushort f2bf(float v) {
    __hip_bfloat16 h = __float2bfloat16(v);
    return *reinterpret_cast<ushort*>(&h);
}
__device__ __forceinline__ float bf2f(ushort u) {
    __hip_bfloat16 h = *reinterpret_cast<__hip_bfloat16*>(&u);
    return __bfloat162float(h);
}
__device__ __forceinline__ void split2(float v, ushort& h, ushort& l) {
    h = f2bf(v);
    l = f2bf(v - bf2f(h));
}
__device__ __forceinline__ uint4 pack8(const ushort* s) {
    uint4 r;
    r.x = (uint)s[0] | ((uint)s[1] << 16);
    r.y = (uint)s[2] | ((uint)s[3] << 16);
    r.z = (uint)s[4] | ((uint)s[5] << 16);
    r.w = (uint)s[6] | ((uint)s[7] << 16);
    return r;
}

// ---------------- split L into bf16 hi/lo (once per call) ----------------
__global__ __launch_bounds__(256)
void split_L(const float* __restrict__ L, ushort* __restrict__ Lhi,
             ushort* __restrict__ Llo)
{
    const int e0 = (blockIdx.x * 256 + threadIdx.x) * 8;
    float4 a = *(const float4*)&L[e0];
    float4 b = *(const float4*)&L[e0 + 4];
    float v[8] = {a.x, a.y, a.z, a.w, b.x, b.y, b.z, b.w};
    ushort h[8], l[8];
#pragma unroll
    for (int j = 0; j < 8; ++j) split2(v[j], h[j], l[j]);
    *(uint4*)&Lhi[e0] = pack8(h);
    *(uint4*)&Llo[e0] = pack8(l);
}

// ---------------- z7 = c7*x -> transposed bf16 splits ----------------
__global__ __launch_bounds__(256)
void split_x(const float* __restrict__ x, const float* __restrict__ coeffs,
             ushort* __restrict__ yhiT, ushort* __restrict__ yloT)
{
    __shared__ float tile[64][65];
    const float c = coeffs[KORD - 1];
    const int m0 = blockIdx.x * 64, n0 = blockIdx.y * 64;
    const int t = threadIdx.x;
    const int ml = t >> 2, n4 = (t & 3) * 16;
#pragma unroll
    for (int j = 0; j < 4; ++j) {
        float4 v = *(const float4*)&x[(size_t)(m0 + ml) * DDIM + n0 + n4 + j * 4];
        tile[ml][n4 + j * 4 + 0] = c * v.x;
        tile[ml][n4 + j * 4 + 1] = c * v.y;
        tile[ml][n4 + j * 4 + 2] = c * v.z;
        tile[ml][n4 + j * 4 + 3] = c * v.w;
    }
    __syncthreads();
    const int nl = t >> 2, m16 = (t & 3) * 16;
    ushort h[16], l[16];
#pragma unroll
    for (int j = 0; j < 16; ++j) split2(tile[m16 + j][nl], h[j], l[j]);
    const size_t ob = (size_t)(n0 + nl) * NDIM + m0 + m16;
    *(uint4*)&yhiT[ob]     = pack8(h);
    *(uint4*)&yhiT[ob + 8] = pack8(h + 8);
    *(uint4*)&yloT[ob]     = pack8(l);
    *(uint4*)&yloT[ob + 8] = pack8(l + 8);
}

// ---------------- MFMA partial GEMM over one (product, K-half) slice ----------------
// A slices: z>>1==0,1 -> Lhi ; ==2 -> Llo   [4096][4096] bf16 row-major
// B slices: z>>1==1 -> yloT ; else yhiT     [256][4096] bf16 (n-major, k-contig)
__global__ __launch_bounds__(256, 2)
void gemm_part(const ushort* __restrict__ Lhi, const ushort* __restrict__ Llo,
               const ushort* __restrict__ yhiT, const ushort* __restrict__ yloT,
               float* __restrict__ P)
{
    __shared__ ushort As[BM * BK];   // [128][32] (m, k)
    __shared__ ushort Bs[BN * BK];   // [64][32]  (n, k)
    const int nt = blockIdx.x;       // 0..3
    const int mt = blockIdx.y;       // 0..31
    const int z  = blockIdx.z;       // 0..5
    const int prod = z >> 1;
    const int kh = (z & 1) * KHALF;
    const ushort* __restrict__ Ap = (prod == 2) ? Llo : Lhi;
    const ushort* __restrict__ Bp = (prod == 1) ? yloT : yhiT;
    const int m0 = mt * BM, n0 = nt * BN;
    const int t = threadIdx.x;
    const int lane = t & 63, wid = t >> 6;
    const int wr = wid >> 1, wc = wid & 1;   // wave tile 64x32

    f32x4 acc[4][2];
#pragma unroll
    for (int i = 0; i < 4; ++i)
#pragma unroll
        for (int j = 0; j < 2; ++j) acc[i][j] = (f32x4){0.f, 0.f, 0.f, 0.f};

    const int ar = t >> 2;           // staging row within tile
    const int ac = (t & 3) * 8;      // k offset (8 bf16 = 16B)
    const ushort* Ag0 = Ap + (size_t)(m0 + ar) * NDIM + kh + ac;
    const ushort* Ag1 = Ag0 + (size_t)64 * NDIM;
    const ushort* Bg  = Bp + (size_t)(n0 + ar) * NDIM + kh + ac;
    ushort* AsW0 = As + wid * 512;          // wave-uniform LDS bases
    ushort* AsW1 = As + 2048 + wid * 512;
    ushort* BsW  = Bs + wid * 512;

    const int frow = lane & 15;
    const int fk   = (lane >> 4) * 8;

    for (int kt = 0; kt < KHALF; kt += BK) {
        __builtin_amdgcn_global_load_lds(
            (const __attribute__((address_space(1))) uint*)(Ag0 + kt),
            (__attribute__((address_space(3))) uint*)AsW0, 16, 0, 0);
        __builtin_amdgcn_global_load_lds(
            (const __attribute__((address_space(1))) uint*)(Ag1 + kt),
            (__attribute__((address_space(3))) uint*)AsW1, 16, 0, 0);
        __builtin_amdgcn_global_load_lds(
            (const __attribute__((address_space(1))) uint*)(Bg + kt),
            (__attribute__((address_space(3))) uint*)BsW, 16, 0, 0);
        __syncthreads();

        bf16x8 af[4], bfv[2];
#pragma unroll
        for (int i = 0; i < 4; ++i)
            af[i] = *(const bf16x8*)&As[(wr * 64 + i * 16 + frow) * BK + fk];
#pragma unroll
        for (int j = 0; j < 2; ++j)
            bfv[j] = *(const bf16x8*)&Bs[(wc * 32 + j * 16 + frow) * BK + fk];
#pragma unroll
        for (int i = 0; i < 4; ++i)
#pragma unroll
            for (int j = 0; j < 2; ++j)
                acc[i][j] = __builtin_amdgcn_mfma_f32_16x16x32_bf16(
                    af[i], bfv[j], acc[i][j], 0, 0, 0);
        __syncthreads();
    }

    float* Pp = P + (size_t)z * ELEMS;
    const int crow = (lane >> 4) * 4;
    const int ccol = lane & 15;
#pragma unroll
    for (int i = 0; i < 4; ++i)
#pragma unroll
        for (int j = 0; j < 2; ++j)
#pragma unroll
            for (int r = 0; r < 4; ++r)
                Pp[(size_t)(m0 + wr * 64 + i * 16 + crow + r) * DDIM
                   + n0 + wc * 32 + j * 16 + ccol] = acc[i][j][r];
}

// ---------------- z = sum(P) + c*x ; re-split transposed (or final out) ----------------
__global__ __launch_bounds__(256)
void combine(const float* __restrict__ P, const float* __restrict__ x,
             const float* __restrict__ coeffs, const int ci, const int last,
             ushort* __restrict__ yhiT, ushort* __restrict__ yloT,
             float* __restrict__ out)
{
    __shared__ float tile[64][65];
    const float c = coeffs[ci];
    const int m0 = blockIdx.x * 64, n0 = blockIdx.y * 64;
    const int t = threadIdx.x;
    const int ml = t >> 2, n4 = (t & 3) * 16;
    const size_t base = (size_t)(m0 + ml) * DDIM + n0 + n4;
    float acc[16];
#pragma unroll
    for (int j = 0; j < 4; ++j) {
        float4 v = *(const float4*)&x[base + j * 4];
        acc[j * 4 + 0] = c * v.x; acc[j * 4 + 1] = c * v.y;
        acc[j * 4 + 2] = c * v.z; acc[j * 4 + 3] = c * v.w;
    }
#pragma unroll
    for (int s = 0; s < NSLICE; ++s) {
        const float* Pp = P + (size_t)s * ELEMS;
#pragma unroll
        for (int j = 0; j < 4; ++j) {
            float4 v = *(const float4*)&Pp[base + j * 4];
            acc[j * 4 + 0] += v.x; acc[j * 4 + 1] += v.y;
            acc[j * 4 + 2] += v.z; acc[j * 4 + 3] += v.w;
        }
    }
    if (last) {
#pragma unroll
        for (int j = 0; j < 4; ++j) {
            float4 v;
            v.x = acc[j * 4 + 0]; v.y = acc[j * 4 + 1];
            v.z = acc[j * 4 + 2]; v.w = acc[j * 4 + 3];
            *(float4*)&out[base + j * 4] = v;
        }
        return;
    }
#pragma unroll
    for (int j = 0; j < 16; ++j) tile[ml][n4 + j] = acc[j];
    __syncthreads();
    const int nl = t >> 2, m16 = (t & 3) * 16;
    ushort h[16], l[16];
#pragma unroll
    for (int j = 0; j < 16; ++j) split2(tile[m16 + j][nl], h[j], l[j]);
    const size_t ob = (size_t)(n0 + nl) * NDIM + m0 + m16;
    *(uint4*)&yhiT[ob]     = pack8(h);
    *(uint4*)&yhiT[ob + 8] = pack8(h + 8);
    *(uint4*)&yloT[ob]     = pack8(l);
    *(uint4*)&yloT[ob + 8] = pack8(l + 8);
}

extern "C" void kernel_launch(void* const* d_in, const int* in_sizes, int n_in,
                              void* d_out, int out_size, void* d_ws, size_t ws_size,
                              hipStream_t stream)
{
    const float* L      = (const float*)d_in[0];
    const float* x      = (const float*)d_in[1];
    const float* coeffs = (const float*)d_in[2];
    float* out = (float*)d_out;

    // Workspace layout (~96.5 MB total):
    //   Lhi  : 4096*4096 bf16 = 32 MB
    //   Llo  : 32 MB
    //   P    : 6 * 4096*256 f32 = 24 MB
    //   yhiT : 256*4096 bf16 = 2 MB
    //   yloT : 2 MB
    char* w = (char*)d_ws;
    ushort* Lhi  = (ushort*)w;
    ushort* Llo  = (ushort*)(w + (size_t)NDIM * NDIM * 2);
    float*  Pp   = (float*)(w + (size_t)NDIM * NDIM * 4);
    ushort* yhiT = (ushort*)(w + (size_t)NDIM * NDIM * 4 + (size_t)NSLICE * ELEMS * 4);
    ushort* yloT = yhiT + (size_t)DDIM * NDIM;

    split_L<<<NDIM * NDIM / (256 * 8), 256, 0, stream>>>(L, Lhi, Llo);
    split_x<<<dim3(NDIM / 64, DDIM / 64), 256, 0, stream>>>(x, coeffs, yhiT, yloT);

    for (int i = KORD - 2; i >= 0; --i) {   // Horner: z <- L z + c_i x
        gemm_part<<<dim3(DDIM / BN, NDIM / BM, NSLICE), 256, 0, stream>>>(
            Lhi, Llo, yhiT, yloT, Pp);
        combine<<<dim3(NDIM / 64, DDIM / 64), 256, 0, stream>>>(
            Pp, x, coeffs, i, (i == 0) ? 1 : 0, yhiT, yloT, out);
    }
}

// Round 3
// 294.091 us; speedup vs baseline: 2.9937x; 1.4597x over previous
//
#include <hip/hip_runtime.h>
#include <hip/hip_bf16.h>

#define NDIM 4096
#define DDIM 256
#define KORD 8

#define BM 128
#define BN 64
#define BK 32
#define SPLITK 4
#define KSLICE (NDIM / SPLITK)    // 1024
#define NSTEP (KSLICE / BK)       // 32
#define ELEMS (NDIM * DDIM)       // 1048576

typedef __attribute__((ext_vector_type(8))) short bf16x8;
typedef __attribute__((ext_vector_type(4))) float f32x4;

__device__ __forceinline__ ushort f2bf(float v) {
    __hip_bfloat16 h = __float2bfloat16(v);
    return *reinterpret_cast<ushort*>(&h);
}
__device__ __forceinline__ float bf2f(ushort u) {
    __hip_bfloat16 h = *reinterpret_cast<__hip_bfloat16*>(&u);
    return __bfloat162float(h);
}
__device__ __forceinline__ void split2(float v, ushort& h, ushort& l) {
    h = f2bf(v);
    l = f2bf(v - bf2f(h));
}
__device__ __forceinline__ uint4 pack8(const ushort* s) {
    uint4 r;
    r.x = (uint)s[0] | ((uint)s[1] << 16);
    r.y = (uint)s[2] | ((uint)s[3] << 16);
    r.z = (uint)s[4] | ((uint)s[5] << 16);
    r.w = (uint)s[6] | ((uint)s[7] << 16);
    return r;
}

// ---------------- split L into bf16 hi/lo (once per call) ----------------
__global__ __launch_bounds__(256)
void split_L(const float* __restrict__ L, ushort* __restrict__ Lhi,
             ushort* __restrict__ Llo)
{
    const int e0 = (blockIdx.x * 256 + threadIdx.x) * 8;
    float4 a = *(const float4*)&L[e0];
    float4 b = *(const float4*)&L[e0 + 4];
    float v[8] = {a.x, a.y, a.z, a.w, b.x, b.y, b.z, b.w};
    ushort h[8], l[8];
#pragma unroll
    for (int j = 0; j < 8; ++j) split2(v[j], h[j], l[j]);
    *(uint4*)&Lhi[e0] = pack8(h);
    *(uint4*)&Llo[e0] = pack8(l);
}

// ---------------- z7 = c7*x -> transposed bf16 splits ----------------
__global__ __launch_bounds__(256)
void split_x(const float* __restrict__ x, const float* __restrict__ coeffs,
             ushort* __restrict__ yhiT, ushort* __restrict__ yloT)
{
    __shared__ float tile[64][65];
    const float c = coeffs[KORD - 1];
    const int m0 = blockIdx.x * 64, n0 = blockIdx.y * 64;
    const int t = threadIdx.x;
    const int ml = t >> 2, n4 = (t & 3) * 16;
#pragma unroll
    for (int j = 0; j < 4; ++j) {
        float4 v = *(const float4*)&x[(size_t)(m0 + ml) * DDIM + n0 + n4 + j * 4];
        tile[ml][n4 + j * 4 + 0] = c * v.x;
        tile[ml][n4 + j * 4 + 1] = c * v.y;
        tile[ml][n4 + j * 4 + 2] = c * v.z;
        tile[ml][n4 + j * 4 + 3] = c * v.w;
    }
    __syncthreads();
    const int nl = t >> 2, m16 = (t & 3) * 16;
    ushort h[16], l[16];
#pragma unroll
    for (int j = 0; j < 16; ++j) split2(tile[m16 + j][nl], h[j], l[j]);
    const size_t ob = (size_t)(n0 + nl) * NDIM + m0 + m16;
    *(uint4*)&yhiT[ob]     = pack8(h);
    *(uint4*)&yhiT[ob + 8] = pack8(h + 8);
    *(uint4*)&yloT[ob]     = pack8(l);
    *(uint4*)&yloT[ob + 8] = pack8(l + 8);
}

// ---------------- fused 3-product MFMA partial GEMM ----------------
// acc = Lhi*yhi + Lhi*ylo + Llo*yhi, accumulated in one pass per K-slice.
// LDS buffer layout (ushort units): AsHi[0..4095] AsLo[4096..8191]
//                                   BsHi[8192..10239] BsLo[10240..12287]
__global__ __launch_bounds__(256, 2)
void gemm_fused(const ushort* __restrict__ Lhi, const ushort* __restrict__ Llo,
                const ushort* __restrict__ yhiT, const ushort* __restrict__ yloT,
                float* __restrict__ P)
{
    __shared__ ushort lds[2][12288];   // 2 x 24 KB

    // XCD-aware swizzle: 512 blocks, xcd = bid%8 (heuristic). Each XCD gets a
    // contiguous chunk of 16 panels; a panel's 4 nt-blocks are co-located.
    const int bid  = blockIdx.x;
    const int xcd  = bid & 7;
    const int slot = bid >> 3;              // 0..63
    const int nt   = slot & 3;
    const int panel = xcd * 16 + (slot >> 2);   // 0..127
    const int mt = panel & 31;
    const int z  = panel >> 5;              // 0..3 K-slice

    const int m0 = mt * BM, n0 = nt * BN;
    const int kb = z * KSLICE;

    const int t = threadIdx.x;
    const int lane = t & 63, wid = t >> 6;
    const int wr = wid >> 1, wc = wid & 1;  // 2x2 wave grid, wave tile 64x32

    // ---- staging addresses (pre-swizzled global source, linear LDS dest)
    const int srow = t >> 2;                        // 0..63
    const int kswz = ((t & 3) ^ (srow & 3)) * 8;    // XOR k-slot swizzle
    const ushort* aH0 = Lhi + (size_t)(m0 + srow) * NDIM + kb + kswz;
    const ushort* aH1 = aH0 + (size_t)64 * NDIM;
    const ushort* aL0 = Llo + (size_t)(m0 + srow) * NDIM + kb + kswz;
    const ushort* aL1 = aL0 + (size_t)64 * NDIM;
    const ushort* bH  = yhiT + (size_t)(n0 + srow) * NDIM + kb + kswz;
    const ushort* bL  = yloT + (size_t)(n0 + srow) * NDIM + kb + kswz;
    const int wb = wid * 512;   // wave staging base (ushorts)

#define GLD(src, c, dstoff)                                                  \
    __builtin_amdgcn_global_load_lds(                                        \
        (const __attribute__((address_space(1))) uint*)(src),                \
        (__attribute__((address_space(3))) uint*)(&lds[c][dstoff]), 16, 0, 0)

    // ---- fragment read offsets (same XOR involution as the source)
    const int frow = lane & 15;
    const int fsw  = ((lane >> 4) ^ (frow & 3)) * 8;
    const int arB  = (wr * 64 + frow) * 32 + fsw;   // A row-base (ushorts)
    const int brB  = (wc * 32 + frow) * 32 + fsw;   // B row-base (ushorts)

    f32x4 acc[4][2];
#pragma unroll
    for (int i = 0; i < 4; ++i)
#pragma unroll
        for (int j = 0; j < 2; ++j) acc[i][j] = (f32x4){0.f, 0.f, 0.f, 0.f};

    // prologue: stage step 0 into buf 0
    {
        const int ko = 0;
        GLD(aH0 + ko, 0, wb);        GLD(aH1 + ko, 0, 2048 + wb);
        GLD(aL0 + ko, 0, 4096 + wb); GLD(aL1 + ko, 0, 6144 + wb);
        GLD(bH + ko, 0, 8192 + wb);  GLD(bL + ko, 0, 10240 + wb);
    }
    __syncthreads();

    int cur = 0;
    for (int step = 0; step < NSTEP; ++step) {
        if (step + 1 < NSTEP) {     // issue next-tile loads into other buffer
            const int ko = (step + 1) * BK;
            const int c = cur ^ 1;
            GLD(aH0 + ko, c, wb);        GLD(aH1 + ko, c, 2048 + wb);
            GLD(aL0 + ko, c, 4096 + wb); GLD(aL1 + ko, c, 6144 + wb);
            GLD(bH + ko, c, 8192 + wb);  GLD(bL + ko, c, 10240 + wb);
        }

        bf16x8 ah[4], al[4], bh[2], blv[2];
#pragma unroll
        for (int i = 0; i < 4; ++i) {
            ah[i] = *(const bf16x8*)&lds[cur][arB + i * 512];
            al[i] = *(const bf16x8*)&lds[cur][arB + i * 512 + 4096];
        }
#pragma unroll
        for (int j = 0; j < 2; ++j) {
            bh[j]  = *(const bf16x8*)&lds[cur][8192 + brB + j * 512];
            blv[j] = *(const bf16x8*)&lds[cur][10240 + brB + j * 512];
        }
#pragma unroll
        for (int i = 0; i < 4; ++i)
#pragma unroll
            for (int j = 0; j < 2; ++j) {
                acc[i][j] = __builtin_amdgcn_mfma_f32_16x16x32_bf16(
                    ah[i], bh[j], acc[i][j], 0, 0, 0);
                acc[i][j] = __builtin_amdgcn_mfma_f32_16x16x32_bf16(
                    ah[i], blv[j], acc[i][j], 0, 0, 0);
                acc[i][j] = __builtin_amdgcn_mfma_f32_16x16x32_bf16(
                    al[i], bh[j], acc[i][j], 0, 0, 0);
            }
        __syncthreads();   // drains vmcnt(0): next buffer staged & ready
        cur ^= 1;
    }
#undef GLD

    float* Pp = P + (size_t)z * ELEMS;
    const int crow = (lane >> 4) * 4;
    const int ccol = lane & 15;
#pragma unroll
    for (int i = 0; i < 4; ++i)
#pragma unroll
        for (int j = 0; j < 2; ++j)
#pragma unroll
            for (int r = 0; r < 4; ++r)
                Pp[(size_t)(m0 + wr * 64 + i * 16 + crow + r) * DDIM
                   + n0 + wc * 32 + j * 16 + ccol] = acc[i][j][r];
}

// ---------------- z = sum(P) + c*x ; re-split transposed (or final out) ----------------
__global__ __launch_bounds__(256)
void combine(const float* __restrict__ P, const float* __restrict__ x,
             const float* __restrict__ coeffs, const int ci, const int last,
             ushort* __restrict__ yhiT, ushort* __restrict__ yloT,
             float* __restrict__ out)
{
    __shared__ float tile[64][65];
    const float c = coeffs[ci];
    const int m0 = blockIdx.x * 64, n0 = blockIdx.y * 64;
    const int t = threadIdx.x;
    const int ml = t >> 2, n4 = (t & 3) * 16;
    const size_t base = (size_t)(m0 + ml) * DDIM + n0 + n4;
    float acc[16];
#pragma unroll
    for (int j = 0; j < 4; ++j) {
        float4 v = *(const float4*)&x[base + j * 4];
        acc[j * 4 + 0] = c * v.x; acc[j * 4 + 1] = c * v.y;
        acc[j * 4 + 2] = c * v.z; acc[j * 4 + 3] = c * v.w;
    }
#pragma unroll
    for (int s = 0; s < SPLITK; ++s) {
        const float* Pp = P + (size_t)s * ELEMS;
#pragma unroll
        for (int j = 0; j < 4; ++j) {
            float4 v = *(const float4*)&Pp[base + j * 4];
            acc[j * 4 + 0] += v.x; acc[j * 4 + 1] += v.y;
            acc[j * 4 + 2] += v.z; acc[j * 4 + 3] += v.w;
        }
    }
    if (last) {
#pragma unroll
        for (int j = 0; j < 4; ++j) {
            float4 v;
            v.x = acc[j * 4 + 0]; v.y = acc[j * 4 + 1];
            v.z = acc[j * 4 + 2]; v.w = acc[j * 4 + 3];
            *(float4*)&out[base + j * 4] = v;
        }
        return;
    }
#pragma unroll
    for (int j = 0; j < 16; ++j) tile[ml][n4 + j] = acc[j];
    __syncthreads();
    const int nl = t >> 2, m16 = (t & 3) * 16;
    ushort h[16], l[16];
#pragma unroll
    for (int j = 0; j < 16; ++j) split2(tile[m16 + j][nl], h[j], l[j]);
    const size_t ob = (size_t)(n0 + nl) * NDIM + m0 + m16;
    *(uint4*)&yhiT[ob]     = pack8(h);
    *(uint4*)&yhiT[ob + 8] = pack8(h + 8);
    *(uint4*)&yloT[ob]     = pack8(l);
    *(uint4*)&yloT[ob + 8] = pack8(l + 8);
}

extern "C" void kernel_launch(void* const* d_in, const int* in_sizes, int n_in,
                              void* d_out, int out_size, void* d_ws, size_t ws_size,
                              hipStream_t stream)
{
    const float* L      = (const float*)d_in[0];
    const float* x      = (const float*)d_in[1];
    const float* coeffs = (const float*)d_in[2];
    float* out = (float*)d_out;

    // Workspace (~84 MB): Lhi 32MB | Llo 32MB | P 16MB | yhiT 2MB | yloT 2MB
    char* w = (char*)d_ws;
    ushort* Lhi  = (ushort*)w;
    ushort* Llo  = (ushort*)(w + (size_t)NDIM * NDIM * 2);
    float*  Pp   = (float*)(w + (size_t)NDIM * NDIM * 4);
    ushort* yhiT = (ushort*)(w + (size_t)NDIM * NDIM * 4 + (size_t)SPLITK * ELEMS * 4);
    ushort* yloT = yhiT + (size_t)DDIM * NDIM;

    split_L<<<NDIM * NDIM / (256 * 8), 256, 0, stream>>>(L, Lhi, Llo);
    split_x<<<dim3(NDIM / 64, DDIM / 64), 256, 0, stream>>>(x, coeffs, yhiT, yloT);

    for (int i = KORD - 2; i >= 0; --i) {   // Horner: z <- L z + c_i x
        gemm_fused<<<SPLITK * 128, 256, 0, stream>>>(Lhi, Llo, yhiT, yloT, Pp);
        combine<<<dim3(NDIM / 64, DDIM / 64), 256, 0, stream>>>(
            Pp, x, coeffs, i, (i == 0) ? 1 : 0, yhiT, yloT, out);
    }
}